// Round 19
// baseline (74.951 us; speedup 1.0000x reference)
//
#include <hip/hip_runtime.h>
#include <hip/hip_bf16.h>
#include <math.h>

#define NB 8
#define NC 512
#define NN 1024      // H*W
#define NHEADS 8
#define EPSV 1e-5f
#define SC2F 0.06376351307f   // 512^-0.5 * log2(e)

typedef __attribute__((ext_vector_type(8))) short bf16x8;
typedef __attribute__((ext_vector_type(4))) short bf16x4;
typedef __attribute__((ext_vector_type(4))) float f32x4;
typedef __attribute__((ext_vector_type(16))) float f32x16;

#define MFMA16(a,b,c) __builtin_amdgcn_mfma_f32_16x16x32_bf16(a,b,c,0,0,0)
#define MFMA32(a,b,c) __builtin_amdgcn_mfma_f32_32x32x16_bf16(a,b,c,0,0,0)

static __device__ __forceinline__ short f2bf(float f) {
    __hip_bfloat16 h = __float2bfloat16(f);
    return *reinterpret_cast<short*>(&h);
}

static __device__ __forceinline__ unsigned cvt_pk_bf16(float lo, float hi) {
    unsigned r;
    asm("v_cvt_pk_bf16_f32 %0, %1, %2" : "=v"(r) : "v"(lo), "v"(hi));
    return r;
}

static __device__ __forceinline__ void gload16(const void* g, void* l) {
    __builtin_amdgcn_global_load_lds((const __attribute__((address_space(1))) void*)g,
                                     (__attribute__((address_space(3))) void*)l, 16, 0, 0);
}

// ws layout (float offsets):
#define WS_PART_SUM 0            // 1024 ([b][128])
#define WS_PART_SQ  1024         // 1024
#define WS_SG       2048         // 1536 (sum_c W*gamma per qkv row)
#define WS_SB       3584         // 1536 (sum_c W*beta per qkv row)
#define WS_XT    8192                    // bf16 [8][1024][512] (transposed bf16 cast of x)
#define WS_QT    (WS_XT   + 2097152)     // bf16 [64][1024][64]  (d fragment-permuted, pre-scaled)
#define WS_KT    (WS_QT   + 2097152)     // bf16 [64][1024][64]  (d fragment-permuted)
#define WS_V     (WS_KT   + 2097152)     // bf16 [64][64][1024]  (keys permuted within 64-groups)
#define WS_VALST (WS_V    + 2097152)     // bf16 [8][1024][512]
#define WS_WQB   (WS_VALST+ 2097152)     // bf16 [1536][512] (W*gamma)
#define WS_WPB   (WS_WQB  + 393216)      // bf16 [512][512]

// ---------------- prep2: x stats+transpose (blocks 0-1023) | weight prep (1024-1535) ----------------
__global__ __launch_bounds__(256) void prep2_kernel(const float* __restrict__ x,
                                                    const float* __restrict__ gamma,
                                                    const float* __restrict__ beta,
                                                    const float* __restrict__ wq,
                                                    const float* __restrict__ wp,
                                                    float* __restrict__ ws,
                                                    __hip_bfloat16* __restrict__ xT) {
    const int blk = blockIdx.x;
    const int t = threadIdx.x;
    if (blk < 1024) {
        // ---- x tile: read ONCE -> partial stats + bf16 transpose ----
        int nt = blk & 15, ct = (blk >> 4) & 7, b = blk >> 7;
        __shared__ __hip_bfloat16 tb[64][72];
        __shared__ float s1[4], s2[4];
        const float* xb = x + ((size_t)b*512 + ct*64)*1024 + nt*64;
        int cl = t >> 4, n4 = (t & 15) * 4;
        float sum = 0.f, sq = 0.f;
        #pragma unroll
        for (int i = 0; i < 4; i++) {
            int c = i*16 + cl;
            float4 v = *(const float4*)(xb + (size_t)c*1024 + n4);
            sum += v.x + v.y + v.z + v.w;
            sq  += v.x*v.x + v.y*v.y + v.z*v.z + v.w*v.w;
            tb[n4+0][c] = __float2bfloat16(v.x);
            tb[n4+1][c] = __float2bfloat16(v.y);
            tb[n4+2][c] = __float2bfloat16(v.z);
            tb[n4+3][c] = __float2bfloat16(v.w);
        }
        #pragma unroll
        for (int off = 32; off; off >>= 1) {
            sum += __shfl_down(sum, off);
            sq  += __shfl_down(sq,  off);
        }
        int wave = t >> 6, lane = t & 63;
        if (lane == 0) { s1[wave] = sum; s2[wave] = sq; }
        __syncthreads();
        #pragma unroll
        for (int i = 0; i < 2; i++) {
            int idx = i*256 + t;
            int n = idx >> 3, c8 = (idx & 7) * 8;
            *(bf16x8*)(xT + ((size_t)b*1024 + nt*64 + n)*512 + ct*64 + c8) =
                *(const bf16x8*)&tb[n][c8];
        }
        if (t == 0) {
            float a = 0.f, c2 = 0.f;
            #pragma unroll
            for (int w = 0; w < 4; w++) { a += s1[w]; c2 += s2[w]; }
            ws[WS_PART_SUM + b*128 + (blk & 127)] = a;
            ws[WS_PART_SQ  + b*128 + (blk & 127)] = c2;
        }
    } else {
        // ---- weight prep: 3 wq rows -> Wgamma bf16 + Sg/Sb; 128 float4 of wp ----
        const int wblk = blk - 1024;   // 0..511
        __shared__ float sred[2][4];
        __hip_bfloat16* wgb = (__hip_bfloat16*)(ws + WS_WQB);
        const int wave = t >> 6, lane = t & 63;
        float2 gm = *(const float2*)(gamma + 2*t);
        float2 bt = *(const float2*)(beta + 2*t);
        #pragma unroll
        for (int rr = 0; rr < 3; rr++) {
            int r = wblk*3 + rr;
            float2 w = *(const float2*)(wq + (size_t)r*512 + 2*t);
            float wg0 = w.x * gm.x, wg1 = w.y * gm.y;
            *(unsigned*)(wgb + (size_t)r*512 + 2*t) = cvt_pk_bf16(wg0, wg1);
            float sg = wg0 + wg1;
            float sb = w.x*bt.x + w.y*bt.y;
            #pragma unroll
            for (int off = 32; off; off >>= 1) {
                sg += __shfl_down(sg, off);
                sb += __shfl_down(sb, off);
            }
            if (lane == 0) { sred[0][wave] = sg; sred[1][wave] = sb; }
            __syncthreads();
            if (t == 0) {
                float tg = 0.f, tbv = 0.f;
                #pragma unroll
                for (int w2 = 0; w2 < 4; w2++) { tg += sred[0][w2]; tbv += sred[1][w2]; }
                ws[WS_SG + r] = tg;
                ws[WS_SB + r] = tbv;
            }
            __syncthreads();
        }
        if (t < 128) {
            int i = wblk*128 + t;
            float4 v = ((const float4*)wp)[i];
            bf16x4 w4;
            w4[0] = f2bf(v.x); w4[1] = f2bf(v.y); w4[2] = f2bf(v.z); w4[3] = f2bf(v.w);
            *(bf16x4*)((__hip_bfloat16*)(ws + WS_WPB) + (size_t)i*4) = w4;
        }
    }
}

// ---------------- QKV GEMM: 128o x 64n tiles -> 1536 blocks; norm folded into epilogue ----------------
// acc = (W*gamma) . bf16(x); out = rstd*acc + (b + Sb - mu*rstd*Sg)  [Q additionally *SC2F]
__global__ __launch_bounds__(256) void gemm_qkv(const __hip_bfloat16* __restrict__ Aw,
                                                const __hip_bfloat16* __restrict__ Bx,
                                                const float* __restrict__ bias,
                                                const float* __restrict__ ws,
                                                __hip_bfloat16* __restrict__ QTx,
                                                __hip_bfloat16* __restrict__ KTx,
                                                __hip_bfloat16* __restrict__ Vx) {
    __shared__ __align__(16) __hip_bfloat16 lds_raw[12288];  // A 128x64 + B 64x64; tb overlay
    __shared__ float stats_s[2];
    const int bx = blockIdx.x;
    const int swz = (bx & 7) * 192 + (bx >> 3);   // batch-affinity XCD swizzle (1536%8==0)
    const int nt = swz & 15;
    const int ot = (swz >> 4) % 12;
    const int bb = swz / 192;
    const int o0 = ot * 128, n0 = nt * 64;

    const int t = threadIdx.x, wv = t >> 6, l = t & 63;
    const int lr = l & 31, lh = l >> 5;

    const __hip_bfloat16* Ag = Aw + (size_t)o0 * 512;
    const __hip_bfloat16* Bg = Bx + ((size_t)bb * 1024 + n0) * 512;
    __hip_bfloat16* Ab = lds_raw;
    __hip_bfloat16* Bb = lds_raw + 128*64;

    f32x16 acc[2];
    #pragma unroll
    for (int ni = 0; ni < 2; ni++)
        #pragma unroll
        for (int r = 0; r < 16; r++) acc[ni][r] = 0.f;

    for (int k0 = 0; k0 < 512; k0 += 64) {
        __syncthreads();
        #pragma unroll
        for (int p = 0; p < 4; p++) {
            int idx = t + p*256;
            int row = idx >> 3, sl = idx & 7;
            int sk = sl ^ (row & 7);
            gload16(Ag + (size_t)row*512 + k0 + sk*8, Ab + idx*8);
        }
        #pragma unroll
        for (int p = 0; p < 2; p++) {
            int idx = t + p*256;
            int row = idx >> 3, sl = idx & 7;
            int sk = sl ^ (row & 7);
            gload16(Bg + (size_t)row*512 + k0 + sk*8, Bb + idx*8);
        }
        __syncthreads();
        #pragma unroll
        for (int ks = 0; ks < 4; ks++) {
            int arow = wv*32 + lr;
            bf16x8 af = *(const bf16x8*)(Ab + arow*64 + (((ks*2 + lh) ^ (arow & 7)) * 8));
            #pragma unroll
            for (int ni = 0; ni < 2; ni++) {
                int brow = ni*32 + lr;
                bf16x8 bfr = *(const bf16x8*)(Bb + brow*64 + (((ks*2 + lh) ^ (brow & 7)) * 8));
                acc[ni] = MFMA32(af, bfr, acc[ni]);
            }
        }
    }

    // finalize batch stats once per block (wave 0), broadcast via LDS
    if (t < 64) {
        const float* ps = ws + WS_PART_SUM + bb*128;
        const float* pq = ws + WS_PART_SQ  + bb*128;
        float s = ps[t] + ps[t + 64];
        float q = pq[t] + pq[t + 64];
        #pragma unroll
        for (int off = 32; off; off >>= 1) {
            s += __shfl_down(s, off);
            q += __shfl_down(q, off);
        }
        if (t == 0) {
            const float inv = 1.f / (float)(NC * NN);
            float mu  = s * inv;
            float var = q * inv - mu * mu;
            stats_s[0] = mu;
            stats_s[1] = rsqrtf(var + EPSV);
        }
    }
    __syncthreads();
    const float mu = stats_s[0], rstd = stats_s[1];
    const float murs = mu * rstd;

    // C/D map (verified m74/m101): col = lr (-> n), row = (r&3) + 8*(r>>2) + 4*lh (-> o)
    int sec = o0 >> 9;                 // 0=Q 1=K 2=V
    if (sec == 2) {
        int od0 = o0 & 511;
        int mperm = ((lr & 12) << 1) + ((lr & 16) >> 2) + (lr & 3);
        #pragma unroll
        for (int q = 0; q < 4; q++) {
            int ob = wv*32 + 8*q + 4*lh;
            float4 bv  = *(const float4*)(bias + o0 + ob);
            float4 sb4 = *(const float4*)(ws + WS_SB + o0 + ob);
            float4 sg4 = *(const float4*)(ws + WS_SG + o0 + ob);
            #pragma unroll
            for (int j = 0; j < 4; j++) {
                float bcor = bv[j] + sb4[j] - murs * sg4[j];
                int ol = od0 + ob + j;
                int h = ol >> 6, d = ol & 63;
                __hip_bfloat16* dst = Vx + ((size_t)((bb<<3) + h)*64 + d)*1024;
                #pragma unroll
                for (int ni = 0; ni < 2; ni++) {
                    int nn = n0 + ni*32 + mperm;
                    dst[nn] = __float2bfloat16(rstd * acc[ni][q*4+j] + bcor);
                }
            }
        }
    } else {
        const float qs = (sec == 0) ? SC2F : 1.0f;
        __syncthreads();
        __hip_bfloat16* tb = lds_raw;  // [64][136]
        #pragma unroll
        for (int q = 0; q < 4; q++) {
            int ob = wv*32 + 8*q + 4*lh;
            float4 bv  = *(const float4*)(bias + o0 + ob);
            float4 sb4 = *(const float4*)(ws + WS_SB + o0 + ob);
            float4 sg4 = *(const float4*)(ws + WS_SG + o0 + ob);
            #pragma unroll
            for (int ni = 0; ni < 2; ni++) {
                int nn = ni*32 + lr;
                bf16x4 w;
                #pragma unroll
                for (int j = 0; j < 4; j++) {
                    float bcor = bv[j] + sb4[j] - murs * sg4[j];
                    w[j] = f2bf((rstd * acc[ni][q*4+j] + bcor) * qs);
                }
                *(bf16x4*)&tb[(size_t)nn*136 + ob] = w;
            }
        }
        __syncthreads();
        __hip_bfloat16* dst0 = (sec == 0) ? QTx : KTx;
        int h0 = (o0 & 511) >> 6;
        #pragma unroll
        for (int i = 0; i < 4; i++) {
            int idx = i*256 + t;
            int n = idx >> 4, rem = idx & 15;
            int hh = rem >> 3, slot = rem & 7;
            int hf32 = (slot & 4) << 3;
            int g4   = (slot & 3) << 2;
            bf16x4 lo = *(const bf16x4*)&tb[(size_t)n*136 + hh*64 + hf32 + g4];
            bf16x4 hi = *(const bf16x4*)&tb[(size_t)n*136 + hh*64 + hf32 + 16 + g4];
            bf16x8 w;
            w[0]=lo[0]; w[1]=lo[1]; w[2]=lo[2]; w[3]=lo[3];
            w[4]=hi[0]; w[5]=hi[1]; w[6]=hi[2]; w[7]=hi[3];
            *(bf16x8*)(dst0 + ((size_t)((bb<<3) + h0 + hh)*1024 + n0 + n)*64 + slot*8) = w;
        }
    }
}

// ---------------- proj GEMM: 128o x 64n tiles -> 512 blocks (2 blocks/CU) ----------------
__global__ __launch_bounds__(256) void gemm_proj(const __hip_bfloat16* __restrict__ Aw,
                                                 const __hip_bfloat16* __restrict__ Bx,
                                                 const float* __restrict__ bias,
                                                 float* __restrict__ Yout) {
    __shared__ __align__(16) __hip_bfloat16 lds_raw[12288];
    const int bx = blockIdx.x;
    const int swz = (bx & 7) * 64 + (bx >> 3);   // batch-affinity XCD swizzle (512%8==0)
    const int nt = swz & 15;
    const int ot = (swz >> 4) & 3;
    const int bb = swz >> 6;
    const int o0 = ot * 128, n0 = nt * 64;

    const int t = threadIdx.x, wv = t >> 6, l = t & 63;
    const int lr = l & 31, lh = l >> 5;

    const __hip_bfloat16* Ag = Aw + (size_t)o0 * 512;
    const __hip_bfloat16* Bg = Bx + ((size_t)bb * 1024 + n0) * 512;
    __hip_bfloat16* Ab = lds_raw;
    __hip_bfloat16* Bb = lds_raw + 128*64;

    f32x16 acc[2];
    #pragma unroll
    for (int ni = 0; ni < 2; ni++)
        #pragma unroll
        for (int r = 0; r < 16; r++) acc[ni][r] = 0.f;

    for (int k0 = 0; k0 < 512; k0 += 64) {
        __syncthreads();
        #pragma unroll
        for (int p = 0; p < 4; p++) {
            int idx = t + p*256;
            int row = idx >> 3, sl = idx & 7;
            int sk = sl ^ (row & 7);
            gload16(Ag + (size_t)row*512 + k0 + sk*8, Ab + idx*8);
        }
        #pragma unroll
        for (int p = 0; p < 2; p++) {
            int idx = t + p*256;
            int row = idx >> 3, sl = idx & 7;
            int sk = sl ^ (row & 7);
            gload16(Bg + (size_t)row*512 + k0 + sk*8, Bb + idx*8);
        }
        __syncthreads();
        #pragma unroll
        for (int ks = 0; ks < 4; ks++) {
            int arow = wv*32 + lr;
            bf16x8 af = *(const bf16x8*)(Ab + arow*64 + (((ks*2 + lh) ^ (arow & 7)) * 8));
            #pragma unroll
            for (int ni = 0; ni < 2; ni++) {
                int brow = ni*32 + lr;
                bf16x8 bfr = *(const bf16x8*)(Bb + brow*64 + (((ks*2 + lh) ^ (brow & 7)) * 8));
                acc[ni] = MFMA32(af, bfr, acc[ni]);
            }
        }
    }

    #pragma unroll
    for (int q = 0; q < 4; q++) {
        int obase = o0 + wv*32 + 8*q + 4*lh;
        float4 bv = *(const float4*)(bias + obase);
        #pragma unroll
        for (int ni = 0; ni < 2; ni++) {
            int nn = n0 + ni*32 + lr;
            #pragma unroll
            for (int j = 0; j < 4; j++)
                Yout[((size_t)bb*512 + obase + j)*1024 + nn] = acc[ni][q*4+j] + bv[j];
        }
    }
}

// ---------------- MFMA flash attention: 4 waves/block, 64 q/block, 1024 blocks (4/CU) ----------------
// Same per-wave math as round-16; finer barrier domains (4 independent blocks per CU).
__global__ __launch_bounds__(256) void attn_mfma(const __hip_bfloat16* __restrict__ QT,
                                                 const __hip_bfloat16* __restrict__ KT,
                                                 const __hip_bfloat16* __restrict__ Vb,
                                                 __hip_bfloat16* __restrict__ valsT) {
    // XCD-grouped decomposition: all 16 q-tiles of one (b,h) share an XCD
    const int bh = ((blockIdx.x & 7) << 3) | ((blockIdx.x >> 3) & 7);
    const int qt = blockIdx.x >> 6;            // 0..15 (64 queries each)
    const int t = threadIdx.x;                 // 0..255
    const int wv = t >> 6, lane = t & 63;
    const int g = lane >> 4, li = lane & 15;

    const __hip_bfloat16* QTg = QT + (size_t)bh * NN * 64;
    const __hip_bfloat16* KTg = KT + (size_t)bh * NN * 64;
    const __hip_bfloat16* Vg  = Vb + (size_t)bh * 64 * NN;

    __shared__ __align__(16) __hip_bfloat16 k_ls[2*4096];
    __shared__ __align__(16) __hip_bfloat16 v_ls[2*4096];

    const int nq0 = qt*64 + wv*16;

    bf16x8 qf[2];
    {
        const __hip_bfloat16* qp = QTg + (size_t)(nq0 + li) * 64;
        qf[0] = *(const bf16x8*)(qp + 8*g);
        qf[1] = *(const bf16x8*)(qp + 32 + 8*g);
    }

    bf16x8 onesf;
    #pragma unroll
    for (int j = 0; j < 8; j++) onesf[j] = (short)0x3F80;

    float m_run = 0.0f;
    f32x4 o_acc[4], o_l;
    #pragma unroll
    for (int dt = 0; dt < 4; dt++) { o_acc[dt][0]=0.f; o_acc[dt][1]=0.f; o_acc[dt][2]=0.f; o_acc[dt][3]=0.f; }
    o_l[0]=0.f; o_l[1]=0.f; o_l[2]=0.f; o_l[3]=0.f;

    // 2 K-loads + 2 V-loads per thread per chunk (256 threads x 2 x 16B = 8KB each)
    auto STAGE = [&](int buf, int ck) {
        const int mc0 = ck * 64;
        #pragma unroll
        for (int p = 0; p < 2; p++) {
            int idx = t + p*256;
            int row = idx >> 3, sl = idx & 7;
            int sk = sl ^ (row & 7);
            gload16(KTg + (size_t)(mc0+row)*64 + sk*8, k_ls + buf*4096 + idx*8);
            gload16(Vg + (size_t)row*NN + mc0 + sk*8, v_ls + buf*4096 + idx*8);
        }
    };

    STAGE(0, 0);
    __syncthreads();
    int cur = 0;

    for (int ck = 0; ck < 16; ck++) {
        if (ck < 15) STAGE(cur ^ 1, ck + 1);

        const __hip_bfloat16* kb = k_ls + cur*4096;
        const __hip_bfloat16* vb = v_ls + cur*4096;

        f32x4 cini;
        cini[0] = -m_run; cini[1] = -m_run; cini[2] = -m_run; cini[3] = -m_run;
        f32x4 s_acc[4];
        __builtin_amdgcn_s_setprio(1);
        #pragma unroll
        for (int mt = 0; mt < 4; mt++) {
            f32x4 c = cini;
            #pragma unroll
            for (int hf = 0; hf < 2; hf++) {
                int row = mt*16 + li;
                int sl = ((hf<<2) + g) ^ (li & 7);
                bf16x8 kf = *(const bf16x8*)(kb + row*64 + sl*8);
                c = MFMA16(kf, qf[hf], c);
            }
            s_acc[mt] = c;
        }
        __builtin_amdgcn_s_setprio(0);

        float cmax = fmaxf(s_acc[0][0], s_acc[0][1]);
        cmax = fmaxf(fmaxf(cmax, s_acc[0][2]), s_acc[0][3]);
        cmax = fmaxf(fmaxf(cmax, s_acc[1][0]), s_acc[1][1]);
        cmax = fmaxf(fmaxf(cmax, s_acc[1][2]), s_acc[1][3]);
        cmax = fmaxf(fmaxf(cmax, s_acc[2][0]), s_acc[2][1]);
        cmax = fmaxf(fmaxf(cmax, s_acc[2][2]), s_acc[2][3]);
        cmax = fmaxf(fmaxf(cmax, s_acc[3][0]), s_acc[3][1]);
        cmax = fmaxf(fmaxf(cmax, s_acc[3][2]), s_acc[3][3]);
        cmax = fmaxf(cmax, __shfl_xor(cmax, 16));
        cmax = fmaxf(cmax, __shfl_xor(cmax, 32));

        if (ck == 0) {
            #pragma unroll
            for (int mt = 0; mt < 4; mt++) {
                s_acc[mt][0] -= cmax; s_acc[mt][1] -= cmax;
                s_acc[mt][2] -= cmax; s_acc[mt][3] -= cmax;
            }
            m_run = cmax;
        } else if (!__all(cmax <= 8.0f)) {        // defer-max (T13), THR=8 in log2
            float d = fmaxf(cmax, 0.0f);
            float resc = __builtin_amdgcn_exp2f(-d);
            f32x4 rv;
            #pragma unroll
            for (int r = 0; r < 4; r++) rv[r] = __shfl(resc, 4*g + r);
            #pragma unroll
            for (int dt = 0; dt < 4; dt++) {
                o_acc[dt][0]*=rv[0]; o_acc[dt][1]*=rv[1]; o_acc[dt][2]*=rv[2]; o_acc[dt][3]*=rv[3];
            }
            o_l[0]*=rv[0]; o_l[1]*=rv[1]; o_l[2]*=rv[2]; o_l[3]*=rv[3];
            #pragma unroll
            for (int mt = 0; mt < 4; mt++) {
                s_acc[mt][0] -= d; s_acc[mt][1] -= d;
                s_acc[mt][2] -= d; s_acc[mt][3] -= d;
            }
            m_run += d;
        }

        bf16x8 pf[2];
        #pragma unroll
        for (int ks = 0; ks < 2; ks++) {
            union { bf16x8 v; unsigned u[4]; } pk;
            #pragma unroll
            for (int d4 = 0; d4 < 4; d4++) {
                const int i0 = 8*ks + 2*d4, i1 = i0 + 1;
                float e0 = __builtin_amdgcn_exp2f(s_acc[i0>>2][i0&3]);
                float e1 = __builtin_amdgcn_exp2f(s_acc[i1>>2][i1&3]);
                pk.u[d4] = cvt_pk_bf16(e0, e1);
            }
            pf[ks] = pk.v;
        }

        __builtin_amdgcn_s_setprio(1);
        #pragma unroll
        for (int dt = 0; dt < 4; dt++) {
            #pragma unroll
            for (int ks = 0; ks < 2; ks++) {
                int row = dt*16 + li;
                int sl = ((ks<<2) + g) ^ (li & 7);
                bf16x8 vf = *(const bf16x8*)(vb + row*64 + sl*8);
                o_acc[dt] = MFMA16(pf[ks], vf, o_acc[dt]);
            }
        }
        o_l = MFMA16(pf[0], onesf, o_l);
        o_l = MFMA16(pf[1], onesf, o_l);
        __builtin_amdgcn_s_setprio(0);

        __syncthreads();
        cur ^= 1;
    }

    f32x4 lv;
    #pragma unroll
    for (int r = 0; r < 4; r++) lv[r] = 1.0f / o_l[r];
    const int bI = bh >> 3, hI = bh & 7;
    __hip_bfloat16* vt = valsT + (size_t)bI*1024*512 + hI*64;
    #pragma unroll
    for (int dt = 0; dt < 4; dt++)
        #pragma unroll
        for (int r = 0; r < 4; r++)
            vt[(size_t)(nq0 + 4*g + r)*512 + dt*16 + li] = __float2bfloat16(o_acc[dt][r]*lv[r]);
}

extern "C" void kernel_launch(void* const* d_in, const int* in_sizes, int n_in,
                              void* d_out, int out_size, void* d_ws, size_t ws_size,
                              hipStream_t stream) {
    const float* x      = (const float*)d_in[0];
    const float* gamma  = (const float*)d_in[1];
    const float* beta   = (const float*)d_in[2];
    const float* w_qkv  = (const float*)d_in[3];
    const float* b_qkv  = (const float*)d_in[4];
    const float* w_proj = (const float*)d_in[5];
    const float* b_proj = (const float*)d_in[6];
    float* ws   = (float*)d_ws;
    float* out  = (float*)d_out;
    __hip_bfloat16* xT    = (__hip_bfloat16*)(ws + WS_XT);
    __hip_bfloat16* QT    = (__hip_bfloat16*)(ws + WS_QT);
    __hip_bfloat16* KT    = (__hip_bfloat16*)(ws + WS_KT);
    __hip_bfloat16* Vx    = (__hip_bfloat16*)(ws + WS_V);
    __hip_bfloat16* valsT = (__hip_bfloat16*)(ws + WS_VALST);
    __hip_bfloat16* wqb   = (__hip_bfloat16*)(ws + WS_WQB);
    __hip_bfloat16* wpb   = (__hip_bfloat16*)(ws + WS_WPB);

    prep2_kernel<<<dim3(1536), dim3(256), 0, stream>>>(x, gamma, beta, w_qkv, w_proj, ws, xT);
    gemm_qkv<<<dim3(1536), dim3(256), 0, stream>>>(wqb, xT, b_qkv, ws, QT, KT, Vx);
    attn_mfma<<<dim3(1024), dim3(256), 0, stream>>>(QT, KT, Vx, valsT);
    gemm_proj<<<dim3(512), dim3(256), 0, stream>>>(wpb, valsT, b_proj, out);
}

// Round 20
// 68.161 us; speedup vs baseline: 1.0996x; 1.0996x over previous
//
#include <hip/hip_runtime.h>
#include <hip/hip_bf16.h>
#include <math.h>

#define NB 8
#define NC 512
#define NN 1024      // H*W
#define NHEADS 8
#define EPSV 1e-5f
#define SC2F 0.06376351307f   // 512^-0.5 * log2(e)

typedef __attribute__((ext_vector_type(8))) short bf16x8;
typedef __attribute__((ext_vector_type(4))) short bf16x4;
typedef __attribute__((ext_vector_type(4))) float f32x4;
typedef __attribute__((ext_vector_type(16))) float f32x16;

#define MFMA16(a,b,c) __builtin_amdgcn_mfma_f32_16x16x32_bf16(a,b,c,0,0,0)
#define MFMA32(a,b,c) __builtin_amdgcn_mfma_f32_32x32x16_bf16(a,b,c,0,0,0)

static __device__ __forceinline__ short f2bf(float f) {
    __hip_bfloat16 h = __float2bfloat16(f);
    return *reinterpret_cast<short*>(&h);
}

static __device__ __forceinline__ unsigned cvt_pk_bf16(float lo, float hi) {
    unsigned r;
    asm("v_cvt_pk_bf16_f32 %0, %1, %2" : "=v"(r) : "v"(lo), "v"(hi));
    return r;
}

static __device__ __forceinline__ void gload16(const void* g, void* l) {
    __builtin_amdgcn_global_load_lds((const __attribute__((address_space(1))) void*)g,
                                     (__attribute__((address_space(3))) void*)l, 16, 0, 0);
}

// ws layout (float offsets):
#define WS_PART_SUM 0            // 1024 ([b][128])
#define WS_PART_SQ  1024         // 1024
#define WS_SG       2048         // 1536 (sum_c W*gamma per qkv row)
#define WS_SB       3584         // 1536 (sum_c W*beta per qkv row)
#define WS_XT    8192                    // bf16 [8][1024][512] (transposed bf16 cast of x)
#define WS_QT    (WS_XT   + 2097152)     // bf16 [64][1024][64]  (d fragment-permuted, pre-scaled)
#define WS_KT    (WS_QT   + 2097152)     // bf16 [64][1024][64]  (d fragment-permuted)
#define WS_V     (WS_KT   + 2097152)     // bf16 [64][64][1024]  (keys permuted within 64-groups)
#define WS_VALST (WS_V    + 2097152)     // bf16 [8][1024][512]
#define WS_WQB   (WS_VALST+ 2097152)     // bf16 [1536][512] (W*gamma)
#define WS_WPB   (WS_WQB  + 393216)      // bf16 [512][512]

// ---------------- prep2: x stats+transpose (blocks 0-1023) | weight prep (1024-1535) ----------------
__global__ __launch_bounds__(256) void prep2_kernel(const float* __restrict__ x,
                                                    const float* __restrict__ gamma,
                                                    const float* __restrict__ beta,
                                                    const float* __restrict__ wq,
                                                    const float* __restrict__ wp,
                                                    float* __restrict__ ws,
                                                    __hip_bfloat16* __restrict__ xT) {
    const int blk = blockIdx.x;
    const int t = threadIdx.x;
    if (blk < 1024) {
        // ---- x tile: read ONCE -> partial stats + bf16 transpose ----
        int nt = blk & 15, ct = (blk >> 4) & 7, b = blk >> 7;
        __shared__ __hip_bfloat16 tb[64][72];
        __shared__ float s1[4], s2[4];
        const float* xb = x + ((size_t)b*512 + ct*64)*1024 + nt*64;
        int cl = t >> 4, n4 = (t & 15) * 4;
        float sum = 0.f, sq = 0.f;
        #pragma unroll
        for (int i = 0; i < 4; i++) {
            int c = i*16 + cl;
            float4 v = *(const float4*)(xb + (size_t)c*1024 + n4);
            sum += v.x + v.y + v.z + v.w;
            sq  += v.x*v.x + v.y*v.y + v.z*v.z + v.w*v.w;
            tb[n4+0][c] = __float2bfloat16(v.x);
            tb[n4+1][c] = __float2bfloat16(v.y);
            tb[n4+2][c] = __float2bfloat16(v.z);
            tb[n4+3][c] = __float2bfloat16(v.w);
        }
        #pragma unroll
        for (int off = 32; off; off >>= 1) {
            sum += __shfl_down(sum, off);
            sq  += __shfl_down(sq,  off);
        }
        int wave = t >> 6, lane = t & 63;
        if (lane == 0) { s1[wave] = sum; s2[wave] = sq; }
        __syncthreads();
        #pragma unroll
        for (int i = 0; i < 2; i++) {
            int idx = i*256 + t;
            int n = idx >> 3, c8 = (idx & 7) * 8;
            *(bf16x8*)(xT + ((size_t)b*1024 + nt*64 + n)*512 + ct*64 + c8) =
                *(const bf16x8*)&tb[n][c8];
        }
        if (t == 0) {
            float a = 0.f, c2 = 0.f;
            #pragma unroll
            for (int w = 0; w < 4; w++) { a += s1[w]; c2 += s2[w]; }
            ws[WS_PART_SUM + b*128 + (blk & 127)] = a;
            ws[WS_PART_SQ  + b*128 + (blk & 127)] = c2;
        }
    } else {
        // ---- weight prep: 3 wq rows -> Wgamma bf16 + Sg/Sb; 128 float4 of wp ----
        const int wblk = blk - 1024;   // 0..511
        __shared__ float sred[2][4];
        __hip_bfloat16* wgb = (__hip_bfloat16*)(ws + WS_WQB);
        const int wave = t >> 6, lane = t & 63;
        float2 gm = *(const float2*)(gamma + 2*t);
        float2 bt = *(const float2*)(beta + 2*t);
        #pragma unroll
        for (int rr = 0; rr < 3; rr++) {
            int r = wblk*3 + rr;
            float2 w = *(const float2*)(wq + (size_t)r*512 + 2*t);
            float wg0 = w.x * gm.x, wg1 = w.y * gm.y;
            *(unsigned*)(wgb + (size_t)r*512 + 2*t) = cvt_pk_bf16(wg0, wg1);
            float sg = wg0 + wg1;
            float sb = w.x*bt.x + w.y*bt.y;
            #pragma unroll
            for (int off = 32; off; off >>= 1) {
                sg += __shfl_down(sg, off);
                sb += __shfl_down(sb, off);
            }
            if (lane == 0) { sred[0][wave] = sg; sred[1][wave] = sb; }
            __syncthreads();
            if (t == 0) {
                float tg = 0.f, tbv = 0.f;
                #pragma unroll
                for (int w2 = 0; w2 < 4; w2++) { tg += sred[0][w2]; tbv += sred[1][w2]; }
                ws[WS_SG + r] = tg;
                ws[WS_SB + r] = tbv;
            }
            __syncthreads();
        }
        if (t < 128) {
            int i = wblk*128 + t;
            float4 v = ((const float4*)wp)[i];
            bf16x4 w4;
            w4[0] = f2bf(v.x); w4[1] = f2bf(v.y); w4[2] = f2bf(v.z); w4[3] = f2bf(v.w);
            *(bf16x4*)((__hip_bfloat16*)(ws + WS_WPB) + (size_t)i*4) = w4;
        }
    }
}

// ---------------- QKV GEMM: 128o x 64n tiles -> 1536 blocks; norm folded into epilogue ----------------
// acc = (W*gamma) . bf16(x); out = rstd*acc + (b + Sb - mu*rstd*Sg)  [Q additionally *SC2F]
__global__ __launch_bounds__(256) void gemm_qkv(const __hip_bfloat16* __restrict__ Aw,
                                                const __hip_bfloat16* __restrict__ Bx,
                                                const float* __restrict__ bias,
                                                const float* __restrict__ ws,
                                                __hip_bfloat16* __restrict__ QTx,
                                                __hip_bfloat16* __restrict__ KTx,
                                                __hip_bfloat16* __restrict__ Vx) {
    __shared__ __align__(16) __hip_bfloat16 lds_raw[12288];  // A 128x64 + B 64x64; tb overlay
    __shared__ float stats_s[2];
    const int bx = blockIdx.x;
    const int swz = (bx & 7) * 192 + (bx >> 3);   // batch-affinity XCD swizzle (1536%8==0)
    const int nt = swz & 15;
    const int ot = (swz >> 4) % 12;
    const int bb = swz / 192;
    const int o0 = ot * 128, n0 = nt * 64;

    const int t = threadIdx.x, wv = t >> 6, l = t & 63;
    const int lr = l & 31, lh = l >> 5;

    const __hip_bfloat16* Ag = Aw + (size_t)o0 * 512;
    const __hip_bfloat16* Bg = Bx + ((size_t)bb * 1024 + n0) * 512;
    __hip_bfloat16* Ab = lds_raw;
    __hip_bfloat16* Bb = lds_raw + 128*64;

    f32x16 acc[2];
    #pragma unroll
    for (int ni = 0; ni < 2; ni++)
        #pragma unroll
        for (int r = 0; r < 16; r++) acc[ni][r] = 0.f;

    for (int k0 = 0; k0 < 512; k0 += 64) {
        __syncthreads();
        #pragma unroll
        for (int p = 0; p < 4; p++) {
            int idx = t + p*256;
            int row = idx >> 3, sl = idx & 7;
            int sk = sl ^ (row & 7);
            gload16(Ag + (size_t)row*512 + k0 + sk*8, Ab + idx*8);
        }
        #pragma unroll
        for (int p = 0; p < 2; p++) {
            int idx = t + p*256;
            int row = idx >> 3, sl = idx & 7;
            int sk = sl ^ (row & 7);
            gload16(Bg + (size_t)row*512 + k0 + sk*8, Bb + idx*8);
        }
        __syncthreads();
        #pragma unroll
        for (int ks = 0; ks < 4; ks++) {
            int arow = wv*32 + lr;
            bf16x8 af = *(const bf16x8*)(Ab + arow*64 + (((ks*2 + lh) ^ (arow & 7)) * 8));
            #pragma unroll
            for (int ni = 0; ni < 2; ni++) {
                int brow = ni*32 + lr;
                bf16x8 bfr = *(const bf16x8*)(Bb + brow*64 + (((ks*2 + lh) ^ (brow & 7)) * 8));
                acc[ni] = MFMA32(af, bfr, acc[ni]);
            }
        }
    }

    // finalize batch stats once per block (wave 0), broadcast via LDS
    if (t < 64) {
        const float* ps = ws + WS_PART_SUM + bb*128;
        const float* pq = ws + WS_PART_SQ  + bb*128;
        float s = ps[t] + ps[t + 64];
        float q = pq[t] + pq[t + 64];
        #pragma unroll
        for (int off = 32; off; off >>= 1) {
            s += __shfl_down(s, off);
            q += __shfl_down(q, off);
        }
        if (t == 0) {
            const float inv = 1.f / (float)(NC * NN);
            float mu  = s * inv;
            float var = q * inv - mu * mu;
            stats_s[0] = mu;
            stats_s[1] = rsqrtf(var + EPSV);
        }
    }
    __syncthreads();
    const float mu = stats_s[0], rstd = stats_s[1];
    const float murs = mu * rstd;

    // C/D map (verified m74/m101): col = lr (-> n), row = (r&3) + 8*(r>>2) + 4*lh (-> o)
    int sec = o0 >> 9;                 // 0=Q 1=K 2=V
    if (sec == 2) {
        int od0 = o0 & 511;
        int mperm = ((lr & 12) << 1) + ((lr & 16) >> 2) + (lr & 3);
        #pragma unroll
        for (int q = 0; q < 4; q++) {
            int ob = wv*32 + 8*q + 4*lh;
            float4 bv  = *(const float4*)(bias + o0 + ob);
            float4 sb4 = *(const float4*)(ws + WS_SB + o0 + ob);
            float4 sg4 = *(const float4*)(ws + WS_SG + o0 + ob);
            #pragma unroll
            for (int j = 0; j < 4; j++) {
                float bcor = bv[j] + sb4[j] - murs * sg4[j];
                int ol = od0 + ob + j;
                int h = ol >> 6, d = ol & 63;
                __hip_bfloat16* dst = Vx + ((size_t)((bb<<3) + h)*64 + d)*1024;
                #pragma unroll
                for (int ni = 0; ni < 2; ni++) {
                    int nn = n0 + ni*32 + mperm;
                    dst[nn] = __float2bfloat16(rstd * acc[ni][q*4+j] + bcor);
                }
            }
        }
    } else {
        const float qs = (sec == 0) ? SC2F : 1.0f;
        __syncthreads();
        __hip_bfloat16* tb = lds_raw;  // [64][136]
        #pragma unroll
        for (int q = 0; q < 4; q++) {
            int ob = wv*32 + 8*q + 4*lh;
            float4 bv  = *(const float4*)(bias + o0 + ob);
            float4 sb4 = *(const float4*)(ws + WS_SB + o0 + ob);
            float4 sg4 = *(const float4*)(ws + WS_SG + o0 + ob);
            #pragma unroll
            for (int ni = 0; ni < 2; ni++) {
                int nn = ni*32 + lr;
                bf16x4 w;
                #pragma unroll
                for (int j = 0; j < 4; j++) {
                    float bcor = bv[j] + sb4[j] - murs * sg4[j];
                    w[j] = f2bf((rstd * acc[ni][q*4+j] + bcor) * qs);
                }
                *(bf16x4*)&tb[(size_t)nn*136 + ob] = w;
            }
        }
        __syncthreads();
        __hip_bfloat16* dst0 = (sec == 0) ? QTx : KTx;
        int h0 = (o0 & 511) >> 6;
        #pragma unroll
        for (int i = 0; i < 4; i++) {
            int idx = i*256 + t;
            int n = idx >> 4, rem = idx & 15;
            int hh = rem >> 3, slot = rem & 7;
            int hf32 = (slot & 4) << 3;
            int g4   = (slot & 3) << 2;
            bf16x4 lo = *(const bf16x4*)&tb[(size_t)n*136 + hh*64 + hf32 + g4];
            bf16x4 hi = *(const bf16x4*)&tb[(size_t)n*136 + hh*64 + hf32 + 16 + g4];
            bf16x8 w;
            w[0]=lo[0]; w[1]=lo[1]; w[2]=lo[2]; w[3]=lo[3];
            w[4]=hi[0]; w[5]=hi[1]; w[6]=hi[2]; w[7]=hi[3];
            *(bf16x8*)(dst0 + ((size_t)((bb<<3) + h0 + hh)*1024 + n0 + n)*64 + slot*8) = w;
        }
    }
}

// ---------------- proj GEMM: 128o x 64n tiles -> 512 blocks (2 blocks/CU) ----------------
__global__ __launch_bounds__(256) void gemm_proj(const __hip_bfloat16* __restrict__ Aw,
                                                 const __hip_bfloat16* __restrict__ Bx,
                                                 const float* __restrict__ bias,
                                                 float* __restrict__ Yout) {
    __shared__ __align__(16) __hip_bfloat16 lds_raw[12288];
    const int bx = blockIdx.x;
    const int swz = (bx & 7) * 64 + (bx >> 3);   // batch-affinity XCD swizzle (512%8==0)
    const int nt = swz & 15;
    const int ot = (swz >> 4) & 3;
    const int bb = swz >> 6;
    const int o0 = ot * 128, n0 = nt * 64;

    const int t = threadIdx.x, wv = t >> 6, l = t & 63;
    const int lr = l & 31, lh = l >> 5;

    const __hip_bfloat16* Ag = Aw + (size_t)o0 * 512;
    const __hip_bfloat16* Bg = Bx + ((size_t)bb * 1024 + n0) * 512;
    __hip_bfloat16* Ab = lds_raw;
    __hip_bfloat16* Bb = lds_raw + 128*64;

    f32x16 acc[2];
    #pragma unroll
    for (int ni = 0; ni < 2; ni++)
        #pragma unroll
        for (int r = 0; r < 16; r++) acc[ni][r] = 0.f;

    for (int k0 = 0; k0 < 512; k0 += 64) {
        __syncthreads();
        #pragma unroll
        for (int p = 0; p < 4; p++) {
            int idx = t + p*256;
            int row = idx >> 3, sl = idx & 7;
            int sk = sl ^ (row & 7);
            gload16(Ag + (size_t)row*512 + k0 + sk*8, Ab + idx*8);
        }
        #pragma unroll
        for (int p = 0; p < 2; p++) {
            int idx = t + p*256;
            int row = idx >> 3, sl = idx & 7;
            int sk = sl ^ (row & 7);
            gload16(Bg + (size_t)row*512 + k0 + sk*8, Bb + idx*8);
        }
        __syncthreads();
        #pragma unroll
        for (int ks = 0; ks < 4; ks++) {
            int arow = wv*32 + lr;
            bf16x8 af = *(const bf16x8*)(Ab + arow*64 + (((ks*2 + lh) ^ (arow & 7)) * 8));
            #pragma unroll
            for (int ni = 0; ni < 2; ni++) {
                int brow = ni*32 + lr;
                bf16x8 bfr = *(const bf16x8*)(Bb + brow*64 + (((ks*2 + lh) ^ (brow & 7)) * 8));
                acc[ni] = MFMA32(af, bfr, acc[ni]);
            }
        }
    }

    #pragma unroll
    for (int q = 0; q < 4; q++) {
        int obase = o0 + wv*32 + 8*q + 4*lh;
        float4 bv = *(const float4*)(bias + obase);
        #pragma unroll
        for (int ni = 0; ni < 2; ni++) {
            int nn = n0 + ni*32 + lr;
            #pragma unroll
            for (int j = 0; j < 4; j++)
                Yout[((size_t)bb*512 + obase + j)*1024 + nn] = acc[ni][q*4+j] + bv[j];
        }
    }
}

// ---------------- MFMA flash attention (round-16 verified): 8 waves, 2-buffer, C-init m-fold ----------------
__global__ __launch_bounds__(512) void attn_mfma(const __hip_bfloat16* __restrict__ QT,
                                                 const __hip_bfloat16* __restrict__ KT,
                                                 const __hip_bfloat16* __restrict__ Vb,
                                                 __hip_bfloat16* __restrict__ valsT) {
    // XCD-grouped decomposition: all 8 q-tiles of one (b,h) share an XCD
    const int bh = ((blockIdx.x & 7) << 3) | ((blockIdx.x >> 3) & 7);
    const int qt = blockIdx.x >> 6;            // 0..7 (128 queries each)
    const int t = threadIdx.x;                 // 0..511
    const int wv = t >> 6, lane = t & 63;
    const int g = lane >> 4, li = lane & 15;

    const __hip_bfloat16* QTg = QT + (size_t)bh * NN * 64;
    const __hip_bfloat16* KTg = KT + (size_t)bh * NN * 64;
    const __hip_bfloat16* Vg  = Vb + (size_t)bh * 64 * NN;

    __shared__ __align__(16) __hip_bfloat16 k_ls[2*4096];
    __shared__ __align__(16) __hip_bfloat16 v_ls[2*4096];

    const int nq0 = qt*128 + wv*16;

    bf16x8 qf[2];
    {
        const __hip_bfloat16* qp = QTg + (size_t)(nq0 + li) * 64;
        qf[0] = *(const bf16x8*)(qp + 8*g);
        qf[1] = *(const bf16x8*)(qp + 32 + 8*g);
    }

    bf16x8 onesf;
    #pragma unroll
    for (int j = 0; j < 8; j++) onesf[j] = (short)0x3F80;

    float m_run = 0.0f;
    f32x4 o_acc[4], o_l;
    #pragma unroll
    for (int dt = 0; dt < 4; dt++) { o_acc[dt][0]=0.f; o_acc[dt][1]=0.f; o_acc[dt][2]=0.f; o_acc[dt][3]=0.f; }
    o_l[0]=0.f; o_l[1]=0.f; o_l[2]=0.f; o_l[3]=0.f;

    auto STAGE = [&](int buf, int ck) {
        const int mc0 = ck * 64;
        int row = t >> 3, sl = t & 7;
        int sk = sl ^ (row & 7);
        gload16(KTg + (size_t)(mc0+row)*64 + sk*8, k_ls + buf*4096 + t*8);
        gload16(Vg + (size_t)row*NN + mc0 + sk*8, v_ls + buf*4096 + t*8);
    };

    STAGE(0, 0);
    __syncthreads();
    int cur = 0;

    for (int ck = 0; ck < 16; ck++) {
        if (ck < 15) STAGE(cur ^ 1, ck + 1);

        const __hip_bfloat16* kb = k_ls + cur*4096;
        const __hip_bfloat16* vb = v_ls + cur*4096;

        f32x4 cini;
        cini[0] = -m_run; cini[1] = -m_run; cini[2] = -m_run; cini[3] = -m_run;
        f32x4 s_acc[4];
        __builtin_amdgcn_s_setprio(1);
        #pragma unroll
        for (int mt = 0; mt < 4; mt++) {
            f32x4 c = cini;
            #pragma unroll
            for (int hf = 0; hf < 2; hf++) {
                int row = mt*16 + li;
                int sl = ((hf<<2) + g) ^ (li & 7);
                bf16x8 kf = *(const bf16x8*)(kb + row*64 + sl*8);
                c = MFMA16(kf, qf[hf], c);
            }
            s_acc[mt] = c;
        }
        __builtin_amdgcn_s_setprio(0);

        float cmax = fmaxf(s_acc[0][0], s_acc[0][1]);
        cmax = fmaxf(fmaxf(cmax, s_acc[0][2]), s_acc[0][3]);
        cmax = fmaxf(fmaxf(cmax, s_acc[1][0]), s_acc[1][1]);
        cmax = fmaxf(fmaxf(cmax, s_acc[1][2]), s_acc[1][3]);
        cmax = fmaxf(fmaxf(cmax, s_acc[2][0]), s_acc[2][1]);
        cmax = fmaxf(fmaxf(cmax, s_acc[2][2]), s_acc[2][3]);
        cmax = fmaxf(fmaxf(cmax, s_acc[3][0]), s_acc[3][1]);
        cmax = fmaxf(fmaxf(cmax, s_acc[3][2]), s_acc[3][3]);
        cmax = fmaxf(cmax, __shfl_xor(cmax, 16));
        cmax = fmaxf(cmax, __shfl_xor(cmax, 32));

        if (ck == 0) {
            #pragma unroll
            for (int mt = 0; mt < 4; mt++) {
                s_acc[mt][0] -= cmax; s_acc[mt][1] -= cmax;
                s_acc[mt][2] -= cmax; s_acc[mt][3] -= cmax;
            }
            m_run = cmax;
        } else if (!__all(cmax <= 8.0f)) {        // defer-max (T13), THR=8 in log2
            float d = fmaxf(cmax, 0.0f);
            float resc = __builtin_amdgcn_exp2f(-d);
            f32x4 rv;
            #pragma unroll
            for (int r = 0; r < 4; r++) rv[r] = __shfl(resc, 4*g + r);
            #pragma unroll
            for (int dt = 0; dt < 4; dt++) {
                o_acc[dt][0]*=rv[0]; o_acc[dt][1]*=rv[1]; o_acc[dt][2]*=rv[2]; o_acc[dt][3]*=rv[3];
            }
            o_l[0]*=rv[0]; o_l[1]*=rv[1]; o_l[2]*=rv[2]; o_l[3]*=rv[3];
            #pragma unroll
            for (int mt = 0; mt < 4; mt++) {
                s_acc[mt][0] -= d; s_acc[mt][1] -= d;
                s_acc[mt][2] -= d; s_acc[mt][3] -= d;
            }
            m_run += d;
        }

        bf16x8 pf[2];
        #pragma unroll
        for (int ks = 0; ks < 2; ks++) {
            union { bf16x8 v; unsigned u[4]; } pk;
            #pragma unroll
            for (int d4 = 0; d4 < 4; d4++) {
                const int i0 = 8*ks + 2*d4, i1 = i0 + 1;
                float e0 = __builtin_amdgcn_exp2f(s_acc[i0>>2][i0&3]);
                float e1 = __builtin_amdgcn_exp2f(s_acc[i1>>2][i1&3]);
                pk.u[d4] = cvt_pk_bf16(e0, e1);
            }
            pf[ks] = pk.v;
        }

        __builtin_amdgcn_s_setprio(1);
        #pragma unroll
        for (int dt = 0; dt < 4; dt++) {
            #pragma unroll
            for (int ks = 0; ks < 2; ks++) {
                int row = dt*16 + li;
                int sl = ((ks<<2) + g) ^ (li & 7);
                bf16x8 vf = *(const bf16x8*)(vb + row*64 + sl*8);
                o_acc[dt] = MFMA16(pf[ks], vf, o_acc[dt]);
            }
        }
        o_l = MFMA16(pf[0], onesf, o_l);
        o_l = MFMA16(pf[1], onesf, o_l);
        __builtin_amdgcn_s_setprio(0);

        __syncthreads();
        cur ^= 1;
    }

    f32x4 lv;
    #pragma unroll
    for (int r = 0; r < 4; r++) lv[r] = 1.0f / o_l[r];
    const int bI = bh >> 3, hI = bh & 7;
    __hip_bfloat16* vt = valsT + (size_t)bI*1024*512 + hI*64;
    #pragma unroll
    for (int dt = 0; dt < 4; dt++)
        #pragma unroll
        for (int r = 0; r < 4; r++)
            vt[(size_t)(nq0 + 4*g + r)*512 + dt*16 + li] = __float2bfloat16(o_acc[dt][r]*lv[r]);
}

extern "C" void kernel_launch(void* const* d_in, const int* in_sizes, int n_in,
                              void* d_out, int out_size, void* d_ws, size_t ws_size,
                              hipStream_t stream) {
    const float* x      = (const float*)d_in[0];
    const float* gamma  = (const float*)d_in[1];
    const float* beta   = (const float*)d_in[2];
    const float* w_qkv  = (const float*)d_in[3];
    const float* b_qkv  = (const float*)d_in[4];
    const float* w_proj = (const float*)d_in[5];
    const float* b_proj = (const float*)d_in[6];
    float* ws   = (float*)d_ws;
    float* out  = (float*)d_out;
    __hip_bfloat16* xT    = (__hip_bfloat16*)(ws + WS_XT);
    __hip_bfloat16* QT    = (__hip_bfloat16*)(ws + WS_QT);
    __hip_bfloat16* KT    = (__hip_bfloat16*)(ws + WS_KT);
    __hip_bfloat16* Vx    = (__hip_bfloat16*)(ws + WS_V);
    __hip_bfloat16* valsT = (__hip_bfloat16*)(ws + WS_VALST);
    __hip_bfloat16* wqb   = (__hip_bfloat16*)(ws + WS_WQB);
    __hip_bfloat16* wpb   = (__hip_bfloat16*)(ws + WS_WPB);

    prep2_kernel<<<dim3(1536), dim3(256), 0, stream>>>(x, gamma, beta, w_qkv, w_proj, ws, xT);
    gemm_qkv<<<dim3(1536), dim3(256), 0, stream>>>(wqb, xT, b_qkv, ws, QT, KT, Vx);
    attn_mfma<<<dim3(512), dim3(512), 0, stream>>>(QT, KT, Vx, valsT);
    gemm_proj<<<dim3(512), dim3(256), 0, stream>>>(wpb, valsT, b_proj, out);
}